// Round 2
// baseline (172.382 us; speedup 1.0000x reference)
//
#include <hip/hip_runtime.h>

#define Bn 8
#define Nn 16384
#define Cn 256
#define NC 32          // split-K chunks over N
#define CHUNK 512      // Nn / NC
#define NST 16         // stages per chunk (32 cols each)

typedef __attribute__((ext_vector_type(4)))  float f32x4;
typedef __attribute__((ext_vector_type(16))) float f32x16;
typedef __attribute__((ext_vector_type(8)))  __bf16 bf16x8;
typedef __attribute__((ext_vector_type(8)))  unsigned short u16x8;

static __device__ __forceinline__ unsigned short f2bf(float f) {
    unsigned int u = __float_as_uint(f);
    u += 0x7fff + ((u >> 16) & 1);          // RNE
    return (unsigned short)(u >> 16);
}
static __device__ __forceinline__ float bf2f(unsigned short h) {
    return __uint_as_float(((unsigned int)h) << 16);
}
static __device__ __forceinline__ f32x16 mfma16(u16x8 a, u16x8 b, f32x16 c) {
    return __builtin_amdgcn_mfma_f32_32x32x16_bf16(
        __builtin_bit_cast(bf16x8, a), __builtin_bit_cast(bf16x8, b), c, 0, 0, 0);
}

// ---------------- K1: Gram partials (hi/lo bf16, 3 MFMA) + row sums ----------------
// grid = Bn * NC * 2; block = 512 thr (8 waves, 2x4 of 64x64 tiles); 2 blocks/CU.
// Each block computes a 128-row half of the 256x256 Gram partial for its chunk.
__global__ __launch_bounds__(512, 4) void k_gram(
    const float* __restrict__ x, float* __restrict__ gpart,
    float* __restrict__ spart) {
  const int blk  = blockIdx.x;
  const int half = blk & 1;
  const int ck   = (blk >> 1) & (NC - 1);
  const int b    = blk >> 6;                 // 2*NC = 64
  const float* xb = x + (size_t)b * Cn * Nn + (size_t)ck * CHUNK;

  __shared__ __align__(16) char smem[32768];  // h:[0,16K) l:[16K,32K), rows of 64B

  const int t    = threadIdx.x;
  const int lane = t & 63;
  const int w    = t >> 6;
  const int wm = w & 1, wn = w >> 1;          // wave tile: rows half*128+wm*64, cols wn*64
  const int ln = lane & 31;
  const int kh = lane >> 5;

  f32x16 acc[2][2];
#pragma unroll
  for (int m = 0; m < 2; ++m)
#pragma unroll
    for (int n = 0; n < 2; ++n)
#pragma unroll
      for (int i = 0; i < 16; ++i) acc[m][n][i] = 0.f;

  const int rt = t >> 3;    // 0..63 (row group)
  const int c4 = t & 7;     // f32x4 slot within 32-col stage

  float srow[4] = {0.f, 0.f, 0.f, 0.f};
  f32x4 ld[4];
#pragma unroll
  for (int j = 0; j < 4; ++j)
    ld[j] = *(const f32x4*)(xb + (size_t)(rt + 64 * j) * Nn + c4 * 4);

  for (int s = 0; s < NST; ++s) {
    __syncthreads();                          // prior MFMA reads done
#pragma unroll
    for (int j = 0; j < 4; ++j) {
      f32x4 v = ld[j];
      srow[j] += v.x + v.y + v.z + v.w;
      unsigned short hx = f2bf(v.x), hy = f2bf(v.y), hz = f2bf(v.z), hw = f2bf(v.w);
      ushort4 h4 = make_ushort4(hx, hy, hz, hw);
      ushort4 l4 = make_ushort4(f2bf(v.x - bf2f(hx)), f2bf(v.y - bf2f(hy)),
                                f2bf(v.z - bf2f(hz)), f2bf(v.w - bf2f(hw)));
      int row = rt + 64 * j;
      int off = row * 64 + ((c4 * 8) ^ ((row & 3) << 4));   // XOR-swizzle
      *(ushort4*)(smem + off) = h4;
      *(ushort4*)(smem + 16384 + off) = l4;
    }
    __syncthreads();
    if (s + 1 < NST) {                        // prefetch next stage (overlaps MFMA)
#pragma unroll
      for (int j = 0; j < 4; ++j)
        ld[j] = *(const f32x4*)(xb + (size_t)(rt + 64 * j) * Nn + (s + 1) * 32 + c4 * 4);
    }
#pragma unroll
    for (int ks = 0; ks < 2; ++ks) {
      const int koff = ks * 32 + kh * 16;
      u16x8 Ah[2], Al[2], Bh[2], Bl[2];
#pragma unroll
      for (int m = 0; m < 2; ++m) {
        int r = half * 128 + wm * 64 + m * 32 + ln;
        int off = r * 64 + (koff ^ ((r & 3) << 4));
        Ah[m] = *(const u16x8*)(smem + off);
        Al[m] = *(const u16x8*)(smem + 16384 + off);
      }
#pragma unroll
      for (int n = 0; n < 2; ++n) {
        int r = wn * 64 + n * 32 + ln;
        int off = r * 64 + (koff ^ ((r & 3) << 4));
        Bh[n] = *(const u16x8*)(smem + off);
        Bl[n] = *(const u16x8*)(smem + 16384 + off);
      }
#pragma unroll
      for (int m = 0; m < 2; ++m)
#pragma unroll
        for (int n = 0; n < 2; ++n) {
          acc[m][n] = mfma16(Ah[m], Bh[n], acc[m][n]);   // HH + HL + LH
          acc[m][n] = mfma16(Ah[m], Bl[n], acc[m][n]);
          acc[m][n] = mfma16(Al[m], Bh[n], acc[m][n]);
        }
    }
  }

  // row sums: 8 threads (c4 groups) share each row
#pragma unroll
  for (int j = 0; j < 4; ++j) {
    float v = srow[j];
    v += __shfl_xor(v, 1);
    v += __shfl_xor(v, 2);
    v += __shfl_xor(v, 4);
    if ((t & 7) == 0 && half == 0)
      spart[(size_t)(b * NC + ck) * Cn + rt + 64 * j] = v;
  }

  float* gp = gpart + (size_t)(b * NC + ck) * (Cn * Cn);
#pragma unroll
  for (int m = 0; m < 2; ++m)
#pragma unroll
    for (int n = 0; n < 2; ++n)
#pragma unroll
      for (int r2 = 0; r2 < 16; ++r2) {
        int row = half * 128 + wm * 64 + m * 32 + (r2 & 3) + 8 * (r2 >> 2) + 4 * kh;
        int col = wn * 64 + n * 32 + ln;
        gp[row * Cn + col] = acc[m][n][r2];
      }
}

// ---------------- K2: reduce Gram partials + row sums; transpose Wk ----------------
__global__ __launch_bounds__(256) void k_reduce(
    const float* __restrict__ gpart, const float* __restrict__ spart,
    const float* __restrict__ wk, float* __restrict__ G,
    float* __restrict__ sv, float* __restrict__ wkT) {
  const int blk = blockIdx.x, t = threadIdx.x;
  if (blk < 512) {
    const int i4 = blk * 256 + t;             // f32x4 index into [B][256][256]
    const int b  = i4 >> 14;
    const int r  = i4 & 16383;
    const f32x4* base = (const f32x4*)gpart + (size_t)b * NC * 16384 + r;
    f32x4 a0 = base[0];
    f32x4 a1 = base[16384];
    f32x4 a2 = base[2 * 16384];
    f32x4 a3 = base[3 * 16384];
    for (int ck = 4; ck < NC; ck += 4) {
      a0 += base[(size_t)ck * 16384];
      a1 += base[(size_t)(ck + 1) * 16384];
      a2 += base[(size_t)(ck + 2) * 16384];
      a3 += base[(size_t)(ck + 3) * 16384];
    }
    ((f32x4*)G)[i4] = (a0 + a1) + (a2 + a3);
  } else {
    const int bb = blk - 512;                 // 0..7
    float a = 0.f;
    for (int ck = 0; ck < NC; ++ck) a += spart[(size_t)(bb * NC + ck) * Cn + t];
    sv[bb * Cn + t] = a;
#pragma unroll
    for (int j = 0; j < 32; ++j) {
      int k = bb * 32 + j;
      wkT[k * Cn + t] = wk[t * Cn + k];
    }
  }
}

// ---------------- K3: scores = Wq G Wk^T + rank-1 terms; softmax; ccB bf16 ----------------
// ccB layout: [b][kgroup g=c/8][d][c&7] bf16 -> k_out B-reads are lane-contiguous.
__global__ __launch_bounds__(256) void k_scores(
    const float* __restrict__ G, const float* __restrict__ sv,
    const float* __restrict__ wq, const float* __restrict__ wkT,
    const float* __restrict__ bq, const float* __restrict__ bk,
    unsigned short* __restrict__ ccB) {
  const int b    = blockIdx.x >> 5;
  const int tile = blockIdx.x & 31;
  const int c0   = tile * 8;
  const int t    = threadIdx.x;

  __shared__ float wq_l[8][256];
  __shared__ float m1_l[8][256];
  __shared__ float sc_l[8][256];
  __shared__ float s_l[256];
  __shared__ float qs_l[8];
  __shared__ float bq_l[8];
  __shared__ unsigned short cct_l[256][8];

#pragma unroll
  for (int j = 0; j < 8; ++j) wq_l[j][t] = wq[(c0 + j) * Cn + t];
  s_l[t] = sv[b * Cn + t];
  if (t < 8) bq_l[t] = bq[c0 + t];
  __syncthreads();

  float a[8];
#pragma unroll
  for (int r = 0; r < 8; ++r) a[r] = 0.f;
  const float* Gb = G + (size_t)b * 65536;
  for (int k = 0; k < 256; ++k) {
    float g = Gb[k * 256 + t];
#pragma unroll
    for (int r = 0; r < 8; ++r) a[r] += wq_l[r][k] * g;
  }
#pragma unroll
  for (int r = 0; r < 8; ++r) m1_l[r][t] = a[r];

  if (t < 8) {
    float q = 0.f;
    for (int c = 0; c < 256; ++c) q += wq_l[t][c] * s_l[c];
    qs_l[t] = q;
  }
  float kst = 0.f;
  for (int c = 0; c < 256; ++c) kst += wkT[c * 256 + t] * s_l[c];
  __syncthreads();

  float sc[8];
#pragma unroll
  for (int r = 0; r < 8; ++r) sc[r] = 0.f;
  for (int k = 0; k < 256; ++k) {
    float wv = wkT[k * 256 + t];
#pragma unroll
    for (int r = 0; r < 8; ++r) sc[r] += m1_l[r][k] * wv;
  }
  float bkt = bk[t];
#pragma unroll
  for (int r = 0; r < 8; ++r)
    sc_l[r][t] = sc[r] + qs_l[r] * bkt + bq_l[r] * (kst + 16384.f * bkt);
  __syncthreads();

  const int r = t >> 5, sub = t & 31;
  float v[8];
#pragma unroll
  for (int j = 0; j < 8; ++j) v[j] = sc_l[r][sub + 32 * j];
  float mx = v[0];
#pragma unroll
  for (int j = 1; j < 8; ++j) mx = fmaxf(mx, v[j]);
#pragma unroll
  for (int msk = 16; msk >= 1; msk >>= 1) mx = fmaxf(mx, __shfl_xor(mx, msk, 32));
  float se = 0.f;
#pragma unroll
  for (int j = 0; j < 8; ++j) { v[j] = __expf(v[j] - mx); se += v[j]; }
#pragma unroll
  for (int msk = 16; msk >= 1; msk >>= 1) se += __shfl_xor(se, msk, 32);
  float inv = 1.f / se;
#pragma unroll
  for (int j = 0; j < 8; ++j) {
    int d = sub + 32 * j;
    float cc = v[j] * inv + ((d == c0 + r) ? 1.f : 0.f);   // fold residual: cc + I
    cct_l[d][r] = f2bf(cc);
  }
  __syncthreads();
  // d = t, kgroup = tile: contiguous uint4 per thread
  *(uint4*)(ccB + (size_t)b * 65536 + (size_t)(tile * 256 + t) * 8) =
      *(const uint4*)(&cct_l[t][0]);
}

// ---------------- K4: out = x_bf16 @ (cc + I) ----------------
// grid = Bn*256; block = 256 thr (4 waves of 64x64); whole K staged once; 4 blocks/CU.
__global__ __launch_bounds__(256, 4) void k_out(
    const float* __restrict__ x, const unsigned short* __restrict__ ccB,
    float* __restrict__ out) {
  const int blk = blockIdx.x;
  const int b  = blk >> 8;
  const int n0 = (blk & 255) * 64;
  const float* xb = x + (size_t)b * Nn * Cn + (size_t)n0 * Cn;
  const unsigned short* cb = ccB + (size_t)b * 65536;
  float* ob = out + (size_t)b * Nn * Cn + (size_t)n0 * Cn;

  __shared__ __align__(16) char smem[32768];   // [64 rows][512B] bf16, XOR-swizzled

  const int t    = threadIdx.x;
  const int lane = t & 63;
  const int w    = t >> 6;        // 0..3 -> output col group (d = w*64..)
  const int ln = lane & 31;
  const int kh = lane >> 5;

  f32x16 acc[2][2];
#pragma unroll
  for (int m = 0; m < 2; ++m)
#pragma unroll
    for (int n = 0; n < 2; ++n)
#pragma unroll
      for (int i = 0; i < 16; ++i) acc[m][n][i] = 0.f;

  // stage full 64x256 tile as bf16: fully-coalesced loads (4KB/instr)
#pragma unroll
  for (int i = 0; i < 16; ++i) {
    int fi = i * 256 + t;
    f32x4 v = *(const f32x4*)(xb + (size_t)fi * 4);
    int row = fi >> 6, c = fi & 63;
    ushort4 hv = make_ushort4(f2bf(v.x), f2bf(v.y), f2bf(v.z), f2bf(v.w));
    *(ushort4*)(smem + row * 512 + ((c * 8) ^ ((row & 31) << 4))) = hv;
  }
  __syncthreads();

#pragma unroll
  for (int ks = 0; ks < 16; ++ks) {
    u16x8 A[2], Bv[2];
    const int g = ks * 2 + kh;                 // 16B k-group index
#pragma unroll
    for (int m = 0; m < 2; ++m) {
      int row = m * 32 + ln;
      A[m] = *(const u16x8*)(smem + row * 512 + ((g * 16) ^ ((row & 31) << 4)));
    }
#pragma unroll
    for (int n = 0; n < 2; ++n) {
      int d = w * 64 + n * 32 + ln;
      Bv[n] = *(const u16x8*)(cb + (size_t)g * 2048 + (size_t)d * 8);  // contiguous 512B/half-wave
    }
#pragma unroll
    for (int m = 0; m < 2; ++m)
#pragma unroll
      for (int n = 0; n < 2; ++n)
        acc[m][n] = mfma16(A[m], Bv[n], acc[m][n]);
  }

#pragma unroll
  for (int m = 0; m < 2; ++m)
#pragma unroll
    for (int n = 0; n < 2; ++n)
#pragma unroll
      for (int r2 = 0; r2 < 16; ++r2) {
        int row = m * 32 + (r2 & 3) + 8 * (r2 >> 2) + 4 * kh;
        int col = w * 64 + n * 32 + ln;
        ob[(size_t)row * Cn + col] = acc[m][n][r2];
      }
}

extern "C" void kernel_launch(void* const* d_in, const int* in_sizes, int n_in,
                              void* d_out, int out_size, void* d_ws, size_t ws_size,
                              hipStream_t stream) {
  const float* x  = (const float*)d_in[0];
  const float* wq = (const float*)d_in[1];
  const float* bq = (const float*)d_in[2];
  const float* wk = (const float*)d_in[3];
  const float* bk = (const float*)d_in[4];
  float* out = (float*)d_out;

  float* gpart = (float*)d_ws;                          // [B][NC][256][256]
  float* spart = gpart + (size_t)Bn * NC * 65536;       // [B][NC][256]
  float* G     = spart + (size_t)Bn * NC * 256;         // [B][256][256]
  float* sv    = G + (size_t)Bn * 65536;                // [B][256]
  float* wkT   = sv + (size_t)Bn * 256;                 // [256][256]
  unsigned short* ccB = (unsigned short*)(wkT + 65536); // [B][32][256][8] bf16

  hipLaunchKernelGGL(k_gram,   dim3(Bn * NC * 2), dim3(512), 0, stream, x, gpart, spart);
  hipLaunchKernelGGL(k_reduce, dim3(520),         dim3(256), 0, stream, gpart, spart, wk, G, sv, wkT);
  hipLaunchKernelGGL(k_scores, dim3(256),         dim3(256), 0, stream, G, sv, wq, wkT, bq, bk, ccB);
  hipLaunchKernelGGL(k_out,    dim3(Bn * 256),    dim3(256), 0, stream, x, ccB, out);
}

// Round 3
// 161.258 us; speedup vs baseline: 1.0690x; 1.0690x over previous
//
#include <hip/hip_runtime.h>

#define Bn 8
#define Nn 16384
#define Cn 256
#define NC 32          // split-K chunks over N
#define CHUNK 512      // Nn / NC
#define NSTG 8         // stages per chunk (64 cols each)

typedef __attribute__((ext_vector_type(4)))  float f32x4;
typedef __attribute__((ext_vector_type(16))) float f32x16;
typedef __attribute__((ext_vector_type(8)))  __bf16 bf16x8;
typedef __attribute__((ext_vector_type(8)))  _Float16 f16x8;
typedef __attribute__((ext_vector_type(8)))  unsigned short u16x8;

static __device__ __forceinline__ unsigned short f2bf(float f) {
    unsigned int u = __float_as_uint(f);
    u += 0x7fff + ((u >> 16) & 1);          // RNE
    return (unsigned short)(u >> 16);
}
static __device__ __forceinline__ unsigned short f2h(float f) {
    return __builtin_bit_cast(unsigned short, (_Float16)f);
}
static __device__ __forceinline__ f32x16 mfma16h(u16x8 a, u16x8 b, f32x16 c) {
    return __builtin_amdgcn_mfma_f32_32x32x16_f16(
        __builtin_bit_cast(f16x8, a), __builtin_bit_cast(f16x8, b), c, 0, 0, 0);
}
static __device__ __forceinline__ f32x16 mfma16b(u16x8 a, u16x8 b, f32x16 c) {
    return __builtin_amdgcn_mfma_f32_32x32x16_bf16(
        __builtin_bit_cast(bf16x8, a), __builtin_bit_cast(bf16x8, b), c, 0, 0, 0);
}

// ---------------- K1: Gram partials (fp16 single-MFMA) + row sums ----------------
// grid = Bn*NC*2 (half-split rows); block 256 thr = 4 waves (col groups), acc[4][2].
// LDS: 256 rows x 128B fp16, 16B-slot swizzle s^(r&7): conflict-free b128 reads.
__global__ __launch_bounds__(256, 2) void k_gram(
    const float* __restrict__ x, float* __restrict__ gpart,
    float* __restrict__ spart) {
  const int blk  = blockIdx.x;
  const int half = blk & 1;
  const int ck   = (blk >> 1) & (NC - 1);
  const int b    = blk >> 6;                 // 2*NC = 64
  const float* xb = x + (size_t)b * Cn * Nn + (size_t)ck * CHUNK;

  __shared__ __align__(16) char smem[32768];

  const int t    = threadIdx.x;
  const int lane = t & 63;
  const int w    = t >> 6;        // 0..3 col group (cols w*64..)
  const int ln   = lane & 31;
  const int kh   = lane >> 5;

  const int rt = t >> 4;          // 0..15
  const int c4 = t & 15;          // f32x4 slot in 64-col stage

  f32x16 acc[4][2];
#pragma unroll
  for (int m = 0; m < 4; ++m)
#pragma unroll
    for (int n = 0; n < 2; ++n)
#pragma unroll
      for (int i = 0; i < 16; ++i) acc[m][n][i] = 0.f;

  float srow[16];
#pragma unroll
  for (int j = 0; j < 16; ++j) srow[j] = 0.f;

  const float* xrow = xb + (size_t)rt * Nn + c4 * 4;

  for (int s = 0; s < NSTG; ++s) {
#pragma unroll
    for (int j = 0; j < 16; ++j) {
      f32x4 v = *(const f32x4*)(xrow + (size_t)j * (16 * Nn) + s * 64);
      srow[j] += v.x + v.y + v.z + v.w;
      ushort4 h = make_ushort4(f2h(v.x), f2h(v.y), f2h(v.z), f2h(v.w));
      int row = rt + 16 * j;
      *(ushort4*)(smem + row * 128 + 16 * ((c4 >> 1) ^ (row & 7)) + (c4 & 1) * 8) = h;
    }
    __syncthreads();
#pragma unroll
    for (int ks = 0; ks < 4; ++ks) {
      const int sl = ks * 2 + kh;
      u16x8 A[4], Bv[2];
#pragma unroll
      for (int m = 0; m < 4; ++m) {
        int r = half * 128 + m * 32 + ln;
        A[m] = *(const u16x8*)(smem + r * 128 + 16 * (sl ^ (r & 7)));
      }
#pragma unroll
      for (int n = 0; n < 2; ++n) {
        int r = w * 64 + n * 32 + ln;
        Bv[n] = *(const u16x8*)(smem + r * 128 + 16 * (sl ^ (r & 7)));
      }
#pragma unroll
      for (int m = 0; m < 4; ++m)
#pragma unroll
        for (int n = 0; n < 2; ++n)
          acc[m][n] = mfma16h(A[m], Bv[n], acc[m][n]);
    }
    __syncthreads();
  }

  // row sums: 16 c4-threads share each row
#pragma unroll
  for (int j = 0; j < 16; ++j) {
    float v = srow[j];
    v += __shfl_xor(v, 1);
    v += __shfl_xor(v, 2);
    v += __shfl_xor(v, 4);
    v += __shfl_xor(v, 8);
    if (c4 == 0 && half == 0)
      spart[(size_t)(b * NC + ck) * Cn + rt + 16 * j] = v;
  }

  float* gp = gpart + (size_t)(b * NC + ck) * (Cn * Cn);
#pragma unroll
  for (int m = 0; m < 4; ++m)
#pragma unroll
    for (int n = 0; n < 2; ++n)
#pragma unroll
      for (int r2 = 0; r2 < 16; ++r2) {
        int row = half * 128 + m * 32 + (r2 & 3) + 8 * (r2 >> 2) + 4 * kh;
        int col = w * 64 + n * 32 + ln;
        gp[row * Cn + col] = acc[m][n][r2];
      }
}

// ---------------- K2 (k_misc, 8 blocks): sv, wkT transpose, kN = Wk s + N bk ----------------
__global__ __launch_bounds__(256) void k_misc(
    const float* __restrict__ spart, const float* __restrict__ wk,
    const float* __restrict__ bk, float* __restrict__ sv,
    float* __restrict__ wkT, float* __restrict__ kN) {
  const int bb = blockIdx.x, t = threadIdx.x;
  __shared__ float s_l[256];
  float a = 0.f;
  for (int ck = 0; ck < NC; ++ck) a += spart[(size_t)(bb * NC + ck) * Cn + t];
  sv[bb * Cn + t] = a;
  s_l[t] = a;
#pragma unroll
  for (int j = 0; j < 32; ++j) {
    int k = bb * 32 + j;
    wkT[k * Cn + t] = wk[t * Cn + k];
  }
  __syncthreads();
  float k2 = 0.f;
  for (int c = 0; c < 256; ++c) k2 += wk[t * Cn + c] * s_l[c];
  kN[bb * Cn + t] = k2 + 16384.f * bk[t];
}

// ---------------- K3 (k_gk): GK = (sum gpart) @ WkT + s*bk^T  (fp32 VALU) ----------------
// grid = Bn*32; block handles 8 rows. Fuses the gpart reduction (G never materialized).
__global__ __launch_bounds__(256) void k_gk(
    const float* __restrict__ gpart, const float* __restrict__ sv,
    const float* __restrict__ wkT, const float* __restrict__ bk,
    float* __restrict__ GK) {
  const int b = blockIdx.x >> 5, tile = blockIdx.x & 31;
  const int r0 = tile * 8, t = threadIdx.x;
  __shared__ float g_l[8][256];

  float a[8];
#pragma unroll
  for (int j = 0; j < 8; ++j) a[j] = 0.f;
  const float* gp = gpart + (size_t)b * NC * 65536 + r0 * 256 + t;
  for (int ck = 0; ck < NC; ++ck) {
#pragma unroll
    for (int j = 0; j < 8; ++j) a[j] += gp[(size_t)ck * 65536 + j * 256];
  }
#pragma unroll
  for (int j = 0; j < 8; ++j) g_l[j][t] = a[j];
  __syncthreads();

  float acc[8];
#pragma unroll
  for (int r = 0; r < 8; ++r) acc[r] = 0.f;
  for (int k0 = 0; k0 < 256; k0 += 4) {
    float w0 = wkT[(k0 + 0) * 256 + t];
    float w1 = wkT[(k0 + 1) * 256 + t];
    float w2 = wkT[(k0 + 2) * 256 + t];
    float w3 = wkT[(k0 + 3) * 256 + t];
#pragma unroll
    for (int r = 0; r < 8; ++r) {
      f32x4 gv = *(const f32x4*)(&g_l[r][k0]);
      acc[r] += gv.x * w0 + gv.y * w1 + gv.z * w2 + gv.w * w3;
    }
  }
  float bkt = bk[t];
#pragma unroll
  for (int r = 0; r < 8; ++r) {
    float svr = sv[b * 256 + r0 + r];
    GK[((size_t)b * 256 + r0 + r) * 256 + t] = acc[r] + svr * bkt;
  }
}

// ---------------- K4 (k_scores): scores = Wq@GK + bq*kN^T; softmax; ccB(+I) bf16 ----------------
__global__ __launch_bounds__(256) void k_scores(
    const float* __restrict__ wq, const float* __restrict__ GK,
    const float* __restrict__ bq, const float* __restrict__ kN,
    unsigned short* __restrict__ ccB) {
  const int b    = blockIdx.x >> 5;
  const int tile = blockIdx.x & 31;
  const int c0   = tile * 8;
  const int t    = threadIdx.x;

  __shared__ float wq_l[8][256];
  __shared__ float sc_l[8][256];
  __shared__ unsigned short cct_l[256][8];

#pragma unroll
  for (int j = 0; j < 8; ++j) wq_l[j][t] = wq[(c0 + j) * Cn + t];
  __syncthreads();

  float acc[8];
#pragma unroll
  for (int r = 0; r < 8; ++r) acc[r] = 0.f;
  for (int k0 = 0; k0 < 256; k0 += 4) {
    float g0 = GK[((size_t)b * 256 + k0 + 0) * 256 + t];
    float g1 = GK[((size_t)b * 256 + k0 + 1) * 256 + t];
    float g2 = GK[((size_t)b * 256 + k0 + 2) * 256 + t];
    float g3 = GK[((size_t)b * 256 + k0 + 3) * 256 + t];
#pragma unroll
    for (int r = 0; r < 8; ++r) {
      f32x4 qv = *(const f32x4*)(&wq_l[r][k0]);
      acc[r] += qv.x * g0 + qv.y * g1 + qv.z * g2 + qv.w * g3;
    }
  }
  float kNt = kN[b * 256 + t];
#pragma unroll
  for (int r = 0; r < 8; ++r) sc_l[r][t] = acc[r] + bq[c0 + r] * kNt;
  __syncthreads();

  const int r = t >> 5, sub = t & 31;
  float v[8];
#pragma unroll
  for (int j = 0; j < 8; ++j) v[j] = sc_l[r][sub + 32 * j];
  float mx = v[0];
#pragma unroll
  for (int j = 1; j < 8; ++j) mx = fmaxf(mx, v[j]);
#pragma unroll
  for (int msk = 16; msk >= 1; msk >>= 1) mx = fmaxf(mx, __shfl_xor(mx, msk, 32));
  float se = 0.f;
#pragma unroll
  for (int j = 0; j < 8; ++j) { v[j] = __expf(v[j] - mx); se += v[j]; }
#pragma unroll
  for (int msk = 16; msk >= 1; msk >>= 1) se += __shfl_xor(se, msk, 32);
  float inv = 1.f / se;
#pragma unroll
  for (int j = 0; j < 8; ++j) {
    int d = sub + 32 * j;
    float cc = v[j] * inv + ((d == c0 + r) ? 1.f : 0.f);   // fold residual: cc + I
    cct_l[d][r] = f2bf(cc);
  }
  __syncthreads();
  *(uint4*)(ccB + (size_t)b * 65536 + (size_t)(tile * 256 + t) * 8) =
      *(const uint4*)(&cct_l[t][0]);
}

// ---------------- K5: out = x_bf16 @ (cc + I) ----------------
__global__ __launch_bounds__(256, 4) void k_out(
    const float* __restrict__ x, const unsigned short* __restrict__ ccB,
    float* __restrict__ out) {
  const int blk = blockIdx.x;
  const int b  = blk >> 8;
  const int n0 = (blk & 255) * 64;
  const float* xb = x + (size_t)b * Nn * Cn + (size_t)n0 * Cn;
  const unsigned short* cb = ccB + (size_t)b * 65536;
  float* ob = out + (size_t)b * Nn * Cn + (size_t)n0 * Cn;

  __shared__ __align__(16) char smem[32768];   // [64 rows][512B] bf16, XOR-swizzled

  const int t    = threadIdx.x;
  const int lane = t & 63;
  const int w    = t >> 6;        // 0..3 -> output col group
  const int ln = lane & 31;
  const int kh = lane >> 5;

  f32x16 acc[2][2];
#pragma unroll
  for (int m = 0; m < 2; ++m)
#pragma unroll
    for (int n = 0; n < 2; ++n)
#pragma unroll
      for (int i = 0; i < 16; ++i) acc[m][n][i] = 0.f;

#pragma unroll
  for (int i = 0; i < 16; ++i) {
    int fi = i * 256 + t;
    f32x4 v = *(const f32x4*)(xb + (size_t)fi * 4);
    int row = fi >> 6, c = fi & 63;
    ushort4 hv = make_ushort4(f2bf(v.x), f2bf(v.y), f2bf(v.z), f2bf(v.w));
    *(ushort4*)(smem + row * 512 + ((c * 8) ^ ((row & 31) << 4))) = hv;
  }
  __syncthreads();

#pragma unroll
  for (int ks = 0; ks < 16; ++ks) {
    u16x8 A[2], Bv[2];
    const int g = ks * 2 + kh;
#pragma unroll
    for (int m = 0; m < 2; ++m) {
      int row = m * 32 + ln;
      A[m] = *(const u16x8*)(smem + row * 512 + ((g * 16) ^ ((row & 31) << 4)));
    }
#pragma unroll
    for (int n = 0; n < 2; ++n) {
      int d = w * 64 + n * 32 + ln;
      Bv[n] = *(const u16x8*)(cb + (size_t)g * 2048 + (size_t)d * 8);
    }
#pragma unroll
    for (int m = 0; m < 2; ++m)
#pragma unroll
      for (int n = 0; n < 2; ++n)
        acc[m][n] = mfma16b(A[m], Bv[n], acc[m][n]);
  }

#pragma unroll
  for (int m = 0; m < 2; ++m)
#pragma unroll
    for (int n = 0; n < 2; ++n)
#pragma unroll
      for (int r2 = 0; r2 < 16; ++r2) {
        int row = m * 32 + (r2 & 3) + 8 * (r2 >> 2) + 4 * kh;
        int col = w * 64 + n * 32 + ln;
        ob[(size_t)row * Cn + col] = acc[m][n][r2];
      }
}

extern "C" void kernel_launch(void* const* d_in, const int* in_sizes, int n_in,
                              void* d_out, int out_size, void* d_ws, size_t ws_size,
                              hipStream_t stream) {
  const float* x  = (const float*)d_in[0];
  const float* wq = (const float*)d_in[1];
  const float* bq = (const float*)d_in[2];
  const float* wk = (const float*)d_in[3];
  const float* bk = (const float*)d_in[4];
  float* out = (float*)d_out;

  float* gpart = (float*)d_ws;                          // [B][NC][256][256] 64MB
  float* spart = gpart + (size_t)Bn * NC * 65536;       // [B][NC][256]
  float* sv    = spart + (size_t)Bn * NC * 256;         // [B][256]
  float* wkT   = sv + (size_t)Bn * 256;                 // [256][256]
  float* kN    = wkT + 65536;                           // [B][256]
  float* GK    = kN + (size_t)Bn * 256;                 // [B][256][256]
  unsigned short* ccB = (unsigned short*)(GK + (size_t)Bn * 65536); // [B][32][256][8] bf16

  hipLaunchKernelGGL(k_gram,   dim3(Bn * NC * 2), dim3(256), 0, stream, x, gpart, spart);
  hipLaunchKernelGGL(k_misc,   dim3(Bn),          dim3(256), 0, stream, spart, wk, bk, sv, wkT, kN);
  hipLaunchKernelGGL(k_gk,     dim3(Bn * 32),     dim3(256), 0, stream, gpart, sv, wkT, bk, GK);
  hipLaunchKernelGGL(k_scores, dim3(Bn * 32),     dim3(256), 0, stream, wq, GK, bq, kN, ccB);
  hipLaunchKernelGGL(k_out,    dim3(Bn * 256),    dim3(256), 0, stream, x, ccB, out);
}

// Round 4
// 156.648 us; speedup vs baseline: 1.1004x; 1.0294x over previous
//
#include <hip/hip_runtime.h>

#define Bn 8
#define Nn 16384
#define Cn 256
#define NC 32          // split-K chunks over N
#define CHUNK 512      // Nn / NC
#define NSTG 16        // stages per chunk (32 cols each)

typedef __attribute__((ext_vector_type(4)))  float f32x4;
typedef __attribute__((ext_vector_type(16))) float f32x16;
typedef __attribute__((ext_vector_type(8)))  __bf16 bf16x8;
typedef __attribute__((ext_vector_type(8)))  _Float16 f16x8;
typedef __attribute__((ext_vector_type(8)))  unsigned short u16x8;

static __device__ __forceinline__ unsigned short f2bf(float f) {
    unsigned int u = __float_as_uint(f);
    u += 0x7fff + ((u >> 16) & 1);          // RNE
    return (unsigned short)(u >> 16);
}
static __device__ __forceinline__ unsigned short f2h(float f) {
    return __builtin_bit_cast(unsigned short, (_Float16)f);
}
static __device__ __forceinline__ f32x16 mfma16h(u16x8 a, u16x8 b, f32x16 c) {
    return __builtin_amdgcn_mfma_f32_32x32x16_f16(
        __builtin_bit_cast(f16x8, a), __builtin_bit_cast(f16x8, b), c, 0, 0, 0);
}
static __device__ __forceinline__ f32x16 mfma16b(u16x8 a, u16x8 b, f32x16 c) {
    return __builtin_amdgcn_mfma_f32_32x32x16_bf16(
        __builtin_bit_cast(bf16x8, a), __builtin_bit_cast(bf16x8, b), c, 0, 0, 0);
}

// ---------------- K1: Gram partials (fp16) + row sums, channel-rotated stages ----------------
// grid = Bn*NC*2 (row-half split); block 512 thr = 8 waves (2 row-groups x 4 col-groups).
// Stage = 32 cols; order rotated per block: sp = (s + 2*ck + half) & 15 -> HBM channel balance.
// LDS: 2 bufs x [256 rows][80B] fp16 (pad 64->80B): frag reads land on all 8 bank-quads.
__global__ __launch_bounds__(512, 4) void k_gram(
    const float* __restrict__ x, float* __restrict__ gpart,
    float* __restrict__ spart) {
  const int blk  = blockIdx.x;
  const int half = blk & 1;
  const int ck   = (blk >> 1) & (NC - 1);
  const int b    = blk >> 6;                 // 2*NC = 64
  const float* xb = x + (size_t)b * Cn * Nn + (size_t)ck * CHUNK;
  const int rot  = (2 * ck + half) & (NSTG - 1);

  __shared__ __align__(16) char smem[2 * 20480];   // 2 x 256 x 80B

  const int t    = threadIdx.x;
  const int lane = t & 63;
  const int w    = t >> 6;        // 0..7
  const int wm   = w & 1;         // row group (64 rows within the 128-row half)
  const int wn   = w >> 1;        // col group 0..3
  const int ln   = lane & 31;
  const int kh   = lane >> 5;

  const int rt = t >> 3;          // 0..63 staging row
  const int c4 = t & 7;           // f32x4 slot within 32-col stage

  f32x16 acc[2][2];
#pragma unroll
  for (int m = 0; m < 2; ++m)
#pragma unroll
    for (int n = 0; n < 2; ++n)
#pragma unroll
      for (int i = 0; i < 16; ++i) acc[m][n][i] = 0.f;

  float srow[4] = {0.f, 0.f, 0.f, 0.f};
  const float* xrt = xb + (size_t)rt * Nn + c4 * 4;

  f32x4 ld[4];
  {
    const int sp = rot;
#pragma unroll
    for (int j = 0; j < 4; ++j)
      ld[j] = *(const f32x4*)(xrt + (size_t)j * (64 * Nn) + sp * 32);
  }

  for (int s = 0; s < NSTG; ++s) {
    char* buf = smem + (s & 1) * 20480;
    // process current stage regs -> LDS (auto vmcnt wait = the BW drain point)
#pragma unroll
    for (int j = 0; j < 4; ++j) {
      f32x4 v = ld[j];
      srow[j] += v.x + v.y + v.z + v.w;
      ushort4 h = make_ushort4(f2h(v.x), f2h(v.y), f2h(v.z), f2h(v.w));
      int row = rt + 64 * j;
      *(ushort4*)(buf + row * 80 + c4 * 8) = h;
    }
    // issue next stage loads (in flight across the barrier's drain)
    if (s + 1 < NSTG) {
      const int sp = (s + 1 + rot) & (NSTG - 1);
#pragma unroll
      for (int j = 0; j < 4; ++j)
        ld[j] = *(const f32x4*)(xrt + (size_t)j * (64 * Nn) + sp * 32);
    }
    __syncthreads();
#pragma unroll
    for (int ks = 0; ks < 2; ++ks) {
      const int sl = ks * 2 + kh;
      u16x8 A[2], Bv[2];
#pragma unroll
      for (int m = 0; m < 2; ++m) {
        int r = half * 128 + wm * 64 + m * 32 + ln;
        A[m] = *(const u16x8*)(buf + r * 80 + sl * 16);
      }
#pragma unroll
      for (int n = 0; n < 2; ++n) {
        int r = wn * 64 + n * 32 + ln;
        Bv[n] = *(const u16x8*)(buf + r * 80 + sl * 16);
      }
#pragma unroll
      for (int m = 0; m < 2; ++m)
#pragma unroll
        for (int n = 0; n < 2; ++n)
          acc[m][n] = mfma16h(A[m], Bv[n], acc[m][n]);
    }
  }

  // row sums: 8 c4-threads share each row
#pragma unroll
  for (int j = 0; j < 4; ++j) {
    float v = srow[j];
    v += __shfl_xor(v, 1);
    v += __shfl_xor(v, 2);
    v += __shfl_xor(v, 4);
    if (c4 == 0 && half == 0)
      spart[(size_t)(b * NC + ck) * Cn + rt + 64 * j] = v;
  }

  float* gp = gpart + (size_t)(b * NC + ck) * (Cn * Cn);
#pragma unroll
  for (int m = 0; m < 2; ++m)
#pragma unroll
    for (int n = 0; n < 2; ++n)
#pragma unroll
      for (int r2 = 0; r2 < 16; ++r2) {
        int row = half * 128 + wm * 64 + m * 32 + (r2 & 3) + 8 * (r2 >> 2) + 4 * kh;
        int col = wn * 64 + n * 32 + ln;
        gp[row * Cn + col] = acc[m][n][r2];
      }
}

// ---------------- K2 (k_misc, 8 blocks): sv, wkT transpose, kN = Wk s + N bk ----------------
__global__ __launch_bounds__(256) void k_misc(
    const float* __restrict__ spart, const float* __restrict__ wk,
    const float* __restrict__ bk, float* __restrict__ sv,
    float* __restrict__ wkT, float* __restrict__ kN) {
  const int bb = blockIdx.x, t = threadIdx.x;
  __shared__ float s_l[256];
  float a = 0.f;
  for (int ck = 0; ck < NC; ++ck) a += spart[(size_t)(bb * NC + ck) * Cn + t];
  sv[bb * Cn + t] = a;
  s_l[t] = a;
#pragma unroll
  for (int j = 0; j < 32; ++j) {
    int k = bb * 32 + j;
    wkT[k * Cn + t] = wk[t * Cn + k];
  }
  __syncthreads();
  float k2 = 0.f;
  for (int c = 0; c < 256; ++c) k2 += wk[t * Cn + c] * s_l[c];
  kN[bb * Cn + t] = k2 + 16384.f * bk[t];
}

// ---------------- K3 (k_gk): GK = (sum gpart) @ WkT + s*bk^T  (fp32 VALU) ----------------
__global__ __launch_bounds__(256) void k_gk(
    const float* __restrict__ gpart, const float* __restrict__ sv,
    const float* __restrict__ wkT, const float* __restrict__ bk,
    float* __restrict__ GK) {
  const int b = blockIdx.x >> 5, tile = blockIdx.x & 31;
  const int r0 = tile * 8, t = threadIdx.x;
  __shared__ float g_l[8][256];

  float a[8];
#pragma unroll
  for (int j = 0; j < 8; ++j) a[j] = 0.f;
  const float* gp = gpart + (size_t)b * NC * 65536 + r0 * 256 + t;
  for (int ck = 0; ck < NC; ++ck) {
#pragma unroll
    for (int j = 0; j < 8; ++j) a[j] += gp[(size_t)ck * 65536 + j * 256];
  }
#pragma unroll
  for (int j = 0; j < 8; ++j) g_l[j][t] = a[j];
  __syncthreads();

  float acc[8];
#pragma unroll
  for (int r = 0; r < 8; ++r) acc[r] = 0.f;
  for (int k0 = 0; k0 < 256; k0 += 4) {
    float w0 = wkT[(k0 + 0) * 256 + t];
    float w1 = wkT[(k0 + 1) * 256 + t];
    float w2 = wkT[(k0 + 2) * 256 + t];
    float w3 = wkT[(k0 + 3) * 256 + t];
#pragma unroll
    for (int r = 0; r < 8; ++r) {
      f32x4 gv = *(const f32x4*)(&g_l[r][k0]);
      acc[r] += gv.x * w0 + gv.y * w1 + gv.z * w2 + gv.w * w3;
    }
  }
  float bkt = bk[t];
#pragma unroll
  for (int r = 0; r < 8; ++r) {
    float svr = sv[b * 256 + r0 + r];
    GK[((size_t)b * 256 + r0 + r) * 256 + t] = acc[r] + svr * bkt;
  }
}

// ---------------- K4 (k_scores): scores = Wq@GK + bq*kN^T; softmax; ccB(+I) bf16 ----------------
__global__ __launch_bounds__(256) void k_scores(
    const float* __restrict__ wq, const float* __restrict__ GK,
    const float* __restrict__ bq, const float* __restrict__ kN,
    unsigned short* __restrict__ ccB) {
  const int b    = blockIdx.x >> 5;
  const int tile = blockIdx.x & 31;
  const int c0   = tile * 8;
  const int t    = threadIdx.x;

  __shared__ float wq_l[8][256];
  __shared__ float sc_l[8][256];
  __shared__ unsigned short cct_l[256][8];

#pragma unroll
  for (int j = 0; j < 8; ++j) wq_l[j][t] = wq[(c0 + j) * Cn + t];
  __syncthreads();

  float acc[8];
#pragma unroll
  for (int r = 0; r < 8; ++r) acc[r] = 0.f;
  for (int k0 = 0; k0 < 256; k0 += 4) {
    float g0 = GK[((size_t)b * 256 + k0 + 0) * 256 + t];
    float g1 = GK[((size_t)b * 256 + k0 + 1) * 256 + t];
    float g2 = GK[((size_t)b * 256 + k0 + 2) * 256 + t];
    float g3 = GK[((size_t)b * 256 + k0 + 3) * 256 + t];
#pragma unroll
    for (int r = 0; r < 8; ++r) {
      f32x4 qv = *(const f32x4*)(&wq_l[r][k0]);
      acc[r] += qv.x * g0 + qv.y * g1 + qv.z * g2 + qv.w * g3;
    }
  }
  float kNt = kN[b * 256 + t];
#pragma unroll
  for (int r = 0; r < 8; ++r) sc_l[r][t] = acc[r] + bq[c0 + r] * kNt;
  __syncthreads();

  const int r = t >> 5, sub = t & 31;
  float v[8];
#pragma unroll
  for (int j = 0; j < 8; ++j) v[j] = sc_l[r][sub + 32 * j];
  float mx = v[0];
#pragma unroll
  for (int j = 1; j < 8; ++j) mx = fmaxf(mx, v[j]);
#pragma unroll
  for (int msk = 16; msk >= 1; msk >>= 1) mx = fmaxf(mx, __shfl_xor(mx, msk, 32));
  float se = 0.f;
#pragma unroll
  for (int j = 0; j < 8; ++j) { v[j] = __expf(v[j] - mx); se += v[j]; }
#pragma unroll
  for (int msk = 16; msk >= 1; msk >>= 1) se += __shfl_xor(se, msk, 32);
  float inv = 1.f / se;
#pragma unroll
  for (int j = 0; j < 8; ++j) {
    int d = sub + 32 * j;
    float cc = v[j] * inv + ((d == c0 + r) ? 1.f : 0.f);   // fold residual: cc + I
    cct_l[d][r] = f2bf(cc);
  }
  __syncthreads();
  *(uint4*)(ccB + (size_t)b * 65536 + (size_t)(tile * 256 + t) * 8) =
      *(const uint4*)(&cct_l[t][0]);
}

// ---------------- K5: out = x_bf16 @ (cc + I) ----------------
__global__ __launch_bounds__(256, 4) void k_out(
    const float* __restrict__ x, const unsigned short* __restrict__ ccB,
    float* __restrict__ out) {
  const int blk = blockIdx.x;
  const int b  = blk >> 8;
  const int n0 = (blk & 255) * 64;
  const float* xb = x + (size_t)b * Nn * Cn + (size_t)n0 * Cn;
  const unsigned short* cb = ccB + (size_t)b * 65536;
  float* ob = out + (size_t)b * Nn * Cn + (size_t)n0 * Cn;

  __shared__ __align__(16) char smem[32768];   // [64 rows][512B] bf16, XOR-swizzled

  const int t    = threadIdx.x;
  const int lane = t & 63;
  const int w    = t >> 6;        // 0..3 -> output col group
  const int ln = lane & 31;
  const int kh = lane >> 5;

  f32x16 acc[2][2];
#pragma unroll
  for (int m = 0; m < 2; ++m)
#pragma unroll
    for (int n = 0; n < 2; ++n)
#pragma unroll
      for (int i = 0; i < 16; ++i) acc[m][n][i] = 0.f;

#pragma unroll
  for (int i = 0; i < 16; ++i) {
    int fi = i * 256 + t;
    f32x4 v = *(const f32x4*)(xb + (size_t)fi * 4);
    int row = fi >> 6, c = fi & 63;
    ushort4 hv = make_ushort4(f2bf(v.x), f2bf(v.y), f2bf(v.z), f2bf(v.w));
    *(ushort4*)(smem + row * 512 + ((c * 8) ^ ((row & 31) << 4))) = hv;
  }
  __syncthreads();

#pragma unroll
  for (int ks = 0; ks < 16; ++ks) {
    u16x8 A[2], Bv[2];
    const int g = ks * 2 + kh;
#pragma unroll
    for (int m = 0; m < 2; ++m) {
      int row = m * 32 + ln;
      A[m] = *(const u16x8*)(smem + row * 512 + ((g * 16) ^ ((row & 31) << 4)));
    }
#pragma unroll
    for (int n = 0; n < 2; ++n) {
      int d = w * 64 + n * 32 + ln;
      Bv[n] = *(const u16x8*)(cb + (size_t)g * 2048 + (size_t)d * 8);
    }
#pragma unroll
    for (int m = 0; m < 2; ++m)
#pragma unroll
      for (int n = 0; n < 2; ++n)
        acc[m][n] = mfma16b(A[m], Bv[n], acc[m][n]);
  }

#pragma unroll
  for (int m = 0; m < 2; ++m)
#pragma unroll
    for (int n = 0; n < 2; ++n)
#pragma unroll
      for (int r2 = 0; r2 < 16; ++r2) {
        int row = m * 32 + (r2 & 3) + 8 * (r2 >> 2) + 4 * kh;
        int col = w * 64 + n * 32 + ln;
        ob[(size_t)row * Cn + col] = acc[m][n][r2];
      }
}

extern "C" void kernel_launch(void* const* d_in, const int* in_sizes, int n_in,
                              void* d_out, int out_size, void* d_ws, size_t ws_size,
                              hipStream_t stream) {
  const float* x  = (const float*)d_in[0];
  const float* wq = (const float*)d_in[1];
  const float* bq = (const float*)d_in[2];
  const float* wk = (const float*)d_in[3];
  const float* bk = (const float*)d_in[4];
  float* out = (float*)d_out;

  float* gpart = (float*)d_ws;                          // [B][NC][256][256] 64MB
  float* spart = gpart + (size_t)Bn * NC * 65536;       // [B][NC][256]
  float* sv    = spart + (size_t)Bn * NC * 256;         // [B][256]
  float* wkT   = sv + (size_t)Bn * 256;                 // [256][256]
  float* kN    = wkT + 65536;                           // [B][256]
  float* GK    = kN + (size_t)Bn * 256;                 // [B][256][256]
  unsigned short* ccB = (unsigned short*)(GK + (size_t)Bn * 65536); // [B][32][256][8] bf16

  hipLaunchKernelGGL(k_gram,   dim3(Bn * NC * 2), dim3(512), 0, stream, x, gpart, spart);
  hipLaunchKernelGGL(k_misc,   dim3(Bn),          dim3(256), 0, stream, spart, wk, bk, sv, wkT, kN);
  hipLaunchKernelGGL(k_gk,     dim3(Bn * 32),     dim3(256), 0, stream, gpart, sv, wkT, bk, GK);
  hipLaunchKernelGGL(k_scores, dim3(Bn * 32),     dim3(256), 0, stream, wq, GK, bq, kN, ccB);
  hipLaunchKernelGGL(k_out,    dim3(Bn * 256),    dim3(256), 0, stream, x, ccB, out);
}